// Round 1
// baseline (233.273 us; speedup 1.0000x reference)
//
#include <hip/hip_runtime.h>
#include <hip/hip_bf16.h>

typedef __attribute__((ext_vector_type(8))) short vbf8;   // 8 bf16 in 4 VGPRs
typedef __attribute__((ext_vector_type(4))) float vf4;    // MFMA 16x16 accumulator

#define MFMA16(a, b, c) __builtin_amdgcn_mfma_f32_16x16x32_bf16((a), (b), (c), 0, 0, 0)

__device__ __forceinline__ unsigned short f2bf(float f) {
    unsigned int u = __float_as_uint(f);
    u += 0x7fffu + ((u >> 16) & 1u);   // RNE
    return (unsigned short)(u >> 16);
}

// async global->LDS, 16B per lane. LDS dest must be linear (base + lane*16).
__device__ __forceinline__ void gload_lds16(const void* g, void* l) {
    __builtin_amdgcn_global_load_lds(
        (const __attribute__((address_space(1))) unsigned int*)(unsigned long long)g,
        (__attribute__((address_space(3))) unsigned int*)(unsigned long long)l,
        16, 0, 0);
}

// ---------------- f32 -> bf16 conversion ----------------
__global__ void cvt_f32_bf16(const float* __restrict__ in, unsigned short* __restrict__ out, int n4) {
    int i = blockIdx.x * blockDim.x + threadIdx.x;
    if (i < n4) {
        float4 v = ((const float4*)in)[i];
        ushort4 o;
        o.x = f2bf(v.x); o.y = f2bf(v.y); o.z = f2bf(v.z); o.w = f2bf(v.w);
        ((ushort4*)out)[i] = o;
    }
}

// ---------------- GEMM: C[M,N] = A[M,K] * Bt[N,K]^T, bf16 in, f32 acc ----------------
// 128x128 tile, BK=64, 4 waves (2x2 of 64x64). LDS linear, global source pre-swizzled
// so that ds_read at swizzled address is bank-conflict-reduced (XOR of 16B-chunk with row&7).
// EPI=0: write f32 to Cf[M,N].  EPI=1: scatter bf16 into Q/K/V [B*H][T][64].
template <int EPI>
__global__ __launch_bounds__(256) void gemm_bt(
    const unsigned short* __restrict__ A, const unsigned short* __restrict__ Bt,
    int M, int N, int K,
    float* __restrict__ Cf,
    unsigned short* __restrict__ Qo, unsigned short* __restrict__ Ko, unsigned short* __restrict__ Vo)
{
    __shared__ __align__(16) unsigned short sA[128 * 64];
    __shared__ __align__(16) unsigned short sB[128 * 64];

    const int tid = threadIdx.x;
    const int lane = tid & 63;
    const int w = tid >> 6;
    const int wr = w >> 1, wc = w & 1;
    const int l16 = lane & 15, lhi = lane >> 4;
    const int bm = blockIdx.y, bn = blockIdx.x;
    const int row0 = bm * 128, col0 = bn * 128;

    vf4 acc[4][4] = {};

    for (int k0 = 0; k0 < K; k0 += 64) {
        // stage 128x64 A and B tiles: 1024 16B-chunks each... (128 rows x 8 chunks)
#pragma unroll
        for (int i = 0; i < 4; ++i) {
            int p = i * 256 + tid;            // chunk id
            int r = p >> 3, cb = p & 7;
            int cs = cb ^ (r & 7);            // pre-swizzled source chunk
            gload_lds16(A + (size_t)(row0 + r) * K + k0 + (cs << 3), &sA[p << 3]);
            gload_lds16(Bt + (size_t)(col0 + r) * K + k0 + (cs << 3), &sB[p << 3]);
        }
        __syncthreads();
#pragma unroll
        for (int kk = 0; kk < 2; ++kk) {
            const int cb = kk * 4 + lhi;
            vbf8 af[4], bfr[4];
#pragma unroll
            for (int mt = 0; mt < 4; ++mt) {
                int r = wr * 64 + mt * 16 + l16;
                af[mt] = *(const vbf8*)&sA[(r << 6) + ((cb ^ (r & 7)) << 3)];
            }
#pragma unroll
            for (int nt = 0; nt < 4; ++nt) {
                int r = wc * 64 + nt * 16 + l16;
                bfr[nt] = *(const vbf8*)&sB[(r << 6) + ((cb ^ (r & 7)) << 3)];
            }
#pragma unroll
            for (int mt = 0; mt < 4; ++mt)
#pragma unroll
                for (int nt = 0; nt < 4; ++nt)
                    acc[mt][nt] = MFMA16(af[mt], bfr[nt], acc[mt][nt]);
        }
        __syncthreads();
    }

    // epilogue: C/D layout col = lane&15, row = (lane>>4)*4 + r
#pragma unroll
    for (int mt = 0; mt < 4; ++mt) {
#pragma unroll
        for (int nt = 0; nt < 4; ++nt) {
#pragma unroll
            for (int r = 0; r < 4; ++r) {
                int row = row0 + wr * 64 + mt * 16 + lhi * 4 + r;
                int col = col0 + wc * 64 + nt * 16 + l16;
                float v = acc[mt][nt][r];
                if (EPI == 0) {
                    Cf[(size_t)row * N + col] = v;
                } else {
                    // col = which*1024 + h*64 + d ; row = b*2048 + t
                    int which = col >> 10, rem = col & 1023;
                    int h = rem >> 6, d = rem & 63;
                    int b = row >> 11, t = row & 2047;
                    unsigned short* dst = (which == 0) ? Qo : ((which == 1) ? Ko : Vo);
                    dst[(((size_t)(b * 16 + h)) * 2048 + t) * 64 + d] = f2bf(v);
                }
            }
        }
    }
}

// ---------------- causal flash attention ----------------
// Q/K/V: [32 heads][2048][64] bf16. 4 waves per block; block = (bh, 64-row q-tile).
// Each wave owns 16 q rows; K/V tiles of 64 rows staged in LDS (K via global_load_lds
// pre-swizzled; V transposed manually into sVt[d][t], swizzled).
__global__ __launch_bounds__(256) void attn_fwd(
    const unsigned short* __restrict__ Q, const unsigned short* __restrict__ Kp,
    const unsigned short* __restrict__ Vp, unsigned short* __restrict__ att)
{
    __shared__ __align__(16) unsigned short sK[64 * 64];
    __shared__ __align__(16) unsigned short sVt[64 * 64];   // [d][t]
    __shared__ __align__(16) unsigned short sP[4][16 * 64]; // per-wave P tile

    const int tid = threadIdx.x;
    const int lane = tid & 63;
    const int w = tid >> 6;
    const int l16 = lane & 15, lhi = lane >> 4;
    const int qt = blockIdx.x & 31;
    const int bh = blockIdx.x >> 5;
    const size_t hoff = (size_t)bh * 2048 * 64;
    const unsigned short* Qh = Q + hoff;
    const unsigned short* Kh = Kp + hoff;
    const unsigned short* Vh = Vp + hoff;
    const int q0 = qt * 64;

    // Q fragments: A row = lane&15 -> q row (q0 + w*16 + l16), k = kk*32 + lhi*8
    vbf8 qf[2];
#pragma unroll
    for (int kk = 0; kk < 2; ++kk)
        qf[kk] = *(const vbf8*)&Qh[(size_t)(q0 + w * 16 + l16) * 64 + kk * 32 + lhi * 8];

    vf4 oacc[4] = {};
    float mrow[4] = {-1e30f, -1e30f, -1e30f, -1e30f};
    float lrow[4] = {0.f, 0.f, 0.f, 0.f};

    for (int kt = 0; kt <= qt; ++kt) {
        const int k0 = kt * 64;
        // stage K tile (64 rows x 8 chunks = 512 chunks), pre-swizzled source
#pragma unroll
        for (int i = 0; i < 2; ++i) {
            int p = i * 256 + tid;
            int r = p >> 3, cb = p & 7;
            gload_lds16(Kh + (size_t)(k0 + r) * 64 + ((cb ^ (r & 7)) << 3), &sK[p << 3]);
        }
        // stage V transposed: sVt[d][t], swizzled chunks
#pragma unroll
        for (int i = 0; i < 2; ++i) {
            int p = i * 256 + tid;
            int t = p >> 3, d0 = (p & 7) << 3;
            ushort4 v1 = *(const ushort4*)&Vh[(size_t)(k0 + t) * 64 + d0];
            ushort4 v2 = *(const ushort4*)&Vh[(size_t)(k0 + t) * 64 + d0 + 4];
            unsigned short e[8] = {v1.x, v1.y, v1.z, v1.w, v2.x, v2.y, v2.z, v2.w};
#pragma unroll
            for (int j = 0; j < 8; ++j) {
                int d = d0 + j;
                sVt[(d << 6) + ((((t >> 3)) ^ (d & 7)) << 3) + (t & 7)] = e[j];
            }
        }
        __syncthreads();

        // QK^T: sc[nt] holds S[q=lhi*4+r][k = nt*16 + l16]
        vf4 sc[4] = {};
#pragma unroll
        for (int kk = 0; kk < 2; ++kk) {
            const int cb = kk * 4 + lhi;
#pragma unroll
            for (int nt = 0; nt < 4; ++nt) {
                int r = nt * 16 + l16;
                vbf8 kf = *(const vbf8*)&sK[(r << 6) + ((cb ^ (r & 7)) << 3)];
                sc[nt] = MFMA16(qf[kk], kf, sc[nt]);
            }
        }

        // scale + causal mask (only the diagonal tile is partial)
        const bool diag = (kt == qt);
#pragma unroll
        for (int nt = 0; nt < 4; ++nt)
#pragma unroll
            for (int r = 0; r < 4; ++r) {
                float s = sc[nt][r] * 0.125f;
                if (diag) {
                    int qg = w * 16 + lhi * 4 + r;
                    int kg = nt * 16 + l16;
                    if (kg > qg) s = -1e30f;
                }
                sc[nt][r] = s;
            }

        // online softmax, rows owned 16-lane-group-wide
#pragma unroll
        for (int r = 0; r < 4; ++r) {
            float pm = fmaxf(fmaxf(sc[0][r], sc[1][r]), fmaxf(sc[2][r], sc[3][r]));
#pragma unroll
            for (int msk = 1; msk < 16; msk <<= 1)
                pm = fmaxf(pm, __shfl_xor(pm, msk, 64));
            float mn = fmaxf(mrow[r], pm);
            float alpha = __expf(mrow[r] - mn);
            mrow[r] = mn;
            float rs = 0.f;
#pragma unroll
            for (int nt = 0; nt < 4; ++nt) {
                float p = __expf(sc[nt][r] - mn);
                sc[nt][r] = p;
                rs += p;
            }
#pragma unroll
            for (int msk = 1; msk < 16; msk <<= 1)
                rs += __shfl_xor(rs, msk, 64);
            lrow[r] = lrow[r] * alpha + rs;
#pragma unroll
            for (int dt = 0; dt < 4; ++dt) oacc[dt][r] *= alpha;
        }

        // write P (bf16) to this wave's LDS strip, swizzled
        unsigned short* pw = &sP[w][0];
#pragma unroll
        for (int nt = 0; nt < 4; ++nt)
#pragma unroll
            for (int r = 0; r < 4; ++r) {
                int row = lhi * 4 + r, col = nt * 16 + l16;
                pw[(row << 6) + (((col >> 3) ^ (row & 7)) << 3) + (col & 7)] = f2bf(sc[nt][r]);
            }
        __syncthreads();

        // PV: A = P (rows q, k = kv), B = V[k][d] via sVt rows
#pragma unroll
        for (int kk = 0; kk < 2; ++kk) {
            const int cb = kk * 4 + lhi;
            vbf8 pf = *(const vbf8*)&pw[(l16 << 6) + ((cb ^ (l16 & 7)) << 3)];
#pragma unroll
            for (int dt = 0; dt < 4; ++dt) {
                int vr = dt * 16 + l16;
                vbf8 vfr = *(const vbf8*)&sVt[(vr << 6) + ((cb ^ (vr & 7)) << 3)];
                oacc[dt] = MFMA16(pf, vfr, oacc[dt]);
            }
        }
        __syncthreads();
    }

    // normalize + write att[b*2048 + q][h*64 + d] (bf16)
    const int b = bh >> 4, h = bh & 15;
#pragma unroll
    for (int r = 0; r < 4; ++r) {
        float inv = 1.0f / lrow[r];
        int qg = q0 + w * 16 + lhi * 4 + r;
#pragma unroll
        for (int dt = 0; dt < 4; ++dt) {
            int d = dt * 16 + l16;
            att[((size_t)(b * 2048 + qg)) * 1024 + h * 64 + d] = f2bf(oacc[dt][r] * inv);
        }
    }
}

// ---------------- launcher ----------------
extern "C" void kernel_launch(void* const* d_in, const int* in_sizes, int n_in,
                              void* d_out, int out_size, void* d_ws, size_t ws_size,
                              hipStream_t stream) {
    const float* x = (const float*)d_in[0];      // [2,2048,1024]
    const float* w_qkv = (const float*)d_in[1];  // [3072,1024]
    const float* w_out = (const float*)d_in[2];  // [1024,1024]
    float* out = (float*)d_out;                  // [2,2048,1024]

    char* ws = (char*)d_ws;
    unsigned short* xb   = (unsigned short*)(ws);                        // 8 MiB
    unsigned short* wqb  = (unsigned short*)(ws + (8ull << 20));         // 6 MiB
    unsigned short* wob  = (unsigned short*)(ws + (14ull << 20));        // 2 MiB
    unsigned short* Qb   = (unsigned short*)(ws + (16ull << 20));        // 8 MiB
    unsigned short* Kb   = (unsigned short*)(ws + (24ull << 20));        // 8 MiB
    unsigned short* Vb   = (unsigned short*)(ws + (32ull << 20));        // 8 MiB
    unsigned short* attb = (unsigned short*)(ws + (40ull << 20));        // 8 MiB

    // 1) conversions
    cvt_f32_bf16<<<4096, 256, 0, stream>>>(x, xb, (2 * 2048 * 1024) / 4);
    cvt_f32_bf16<<<3072, 256, 0, stream>>>(w_qkv, wqb, (3072 * 1024) / 4);
    cvt_f32_bf16<<<1024, 256, 0, stream>>>(w_out, wob, (1024 * 1024) / 4);

    // 2) QKV projection: [4096,1024] x [3072,1024]^T -> scatter to Q/K/V
    gemm_bt<1><<<dim3(3072 / 128, 4096 / 128), 256, 0, stream>>>(
        xb, wqb, 4096, 3072, 1024, nullptr, Qb, Kb, Vb);

    // 3) causal attention -> attb [4096,1024] bf16
    attn_fwd<<<32 * 32, 256, 0, stream>>>(Qb, Kb, Vb, attb);

    // 4) output projection: [4096,1024] x [1024,1024]^T -> f32 d_out
    gemm_bt<0><<<dim3(1024 / 128, 4096 / 128), 256, 0, stream>>>(
        attb, wob, 4096, 1024, 1024, out, nullptr, nullptr, nullptr);
}

// Round 2
// 152.993 us; speedup vs baseline: 1.5247x; 1.5247x over previous
//
#include <hip/hip_runtime.h>
#include <hip/hip_bf16.h>

typedef __attribute__((ext_vector_type(8))) short vbf8;   // 8 bf16 in 4 VGPRs
typedef __attribute__((ext_vector_type(4))) float vf4;    // MFMA 16x16 accumulator
typedef __attribute__((ext_vector_type(4))) unsigned int vu4;

#define MFMA16(a, b, c) __builtin_amdgcn_mfma_f32_16x16x32_bf16((a), (b), (c), 0, 0, 0)

__device__ __forceinline__ unsigned short f2bf(float f) {
    unsigned int u = __float_as_uint(f);
    u += 0x7fffu + ((u >> 16) & 1u);   // RNE
    return (unsigned short)(u >> 16);
}

// async global->LDS, 16B per lane. LDS dest must be linear (base + lane*16).
__device__ __forceinline__ void gload_lds16(const void* g, void* l) {
    __builtin_amdgcn_global_load_lds(
        (const __attribute__((address_space(1))) unsigned int*)(unsigned long long)g,
        (__attribute__((address_space(3))) unsigned int*)(unsigned long long)l,
        16, 0, 0);
}

// ---------------- f32 -> bf16 conversion ----------------
__global__ void cvt_f32_bf16(const float* __restrict__ in, unsigned short* __restrict__ out, int n4) {
    int i = blockIdx.x * blockDim.x + threadIdx.x;
    if (i < n4) {
        float4 v = ((const float4*)in)[i];
        ushort4 o;
        o.x = f2bf(v.x); o.y = f2bf(v.y); o.z = f2bf(v.z); o.w = f2bf(v.w);
        ((ushort4*)out)[i] = o;
    }
}

// ---------------- GEMM: C[M,N] = A[M,K] * Bt[N,K]^T, bf16 in, f32 acc ----------------
// 128x128 tile, BK=64, 4 waves (2x2 of 64x64). LDS linear, global source pre-swizzled.
// EPI=0: write f32 to Cf[M,N].  EPI=1: scatter bf16 into Q/K [bh][t][64] and V TRANSPOSED [bh][64][2048].
template <int EPI>
__global__ __launch_bounds__(256) void gemm_bt(
    const unsigned short* __restrict__ A, const unsigned short* __restrict__ Bt,
    int M, int N, int K,
    float* __restrict__ Cf,
    unsigned short* __restrict__ Qo, unsigned short* __restrict__ Ko, unsigned short* __restrict__ Vo)
{
    __shared__ __align__(16) unsigned short sA[128 * 64];
    __shared__ __align__(16) unsigned short sB[128 * 64];

    const int tid = threadIdx.x;
    const int lane = tid & 63;
    const int w = tid >> 6;
    const int wr = w >> 1, wc = w & 1;
    const int l16 = lane & 15, lhi = lane >> 4;
    const int bm = blockIdx.y, bn = blockIdx.x;
    const int row0 = bm * 128, col0 = bn * 128;

    vf4 acc[4][4] = {};

    for (int k0 = 0; k0 < K; k0 += 64) {
#pragma unroll
        for (int i = 0; i < 4; ++i) {
            int p = i * 256 + tid;            // chunk id
            int r = p >> 3, cb = p & 7;
            int cs = cb ^ (r & 7);            // pre-swizzled source chunk
            gload_lds16(A + (size_t)(row0 + r) * K + k0 + (cs << 3), &sA[p << 3]);
            gload_lds16(Bt + (size_t)(col0 + r) * K + k0 + (cs << 3), &sB[p << 3]);
        }
        __syncthreads();
#pragma unroll
        for (int kk = 0; kk < 2; ++kk) {
            const int cb = kk * 4 + lhi;
            vbf8 af[4], bfr[4];
#pragma unroll
            for (int mt = 0; mt < 4; ++mt) {
                int r = wr * 64 + mt * 16 + l16;
                af[mt] = *(const vbf8*)&sA[(r << 6) + ((cb ^ (r & 7)) << 3)];
            }
#pragma unroll
            for (int nt = 0; nt < 4; ++nt) {
                int r = wc * 64 + nt * 16 + l16;
                bfr[nt] = *(const vbf8*)&sB[(r << 6) + ((cb ^ (r & 7)) << 3)];
            }
#pragma unroll
            for (int mt = 0; mt < 4; ++mt)
#pragma unroll
                for (int nt = 0; nt < 4; ++nt)
                    acc[mt][nt] = MFMA16(af[mt], bfr[nt], acc[mt][nt]);
        }
        __syncthreads();
    }

    // epilogue: C/D layout col = lane&15, row = (lane>>4)*4 + r
#pragma unroll
    for (int mt = 0; mt < 4; ++mt) {
#pragma unroll
        for (int nt = 0; nt < 4; ++nt) {
#pragma unroll
            for (int r = 0; r < 4; ++r) {
                int row = row0 + wr * 64 + mt * 16 + lhi * 4 + r;
                int col = col0 + wc * 64 + nt * 16 + l16;
                float v = acc[mt][nt][r];
                if (EPI == 0) {
                    Cf[(size_t)row * N + col] = v;
                } else {
                    // col = which*1024 + h*64 + d ; row = b*2048 + t
                    int which = col >> 10, rem = col & 1023;
                    int h = rem >> 6, d = rem & 63;
                    int b = row >> 11, t = row & 2047;
                    size_t bh = (size_t)(b * 16 + h);
                    if (which == 0)      Qo[(bh * 2048 + t) * 64 + d] = f2bf(v);
                    else if (which == 1) Ko[(bh * 2048 + t) * 64 + d] = f2bf(v);
                    else                 Vo[(bh * 64 + d) * 2048 + t] = f2bf(v);  // transposed
                }
            }
        }
    }
}

// ---------------- causal flash attention, swapped-operand in-register softmax ----------------
// Q/K: [32 bh][2048][64] bf16; Vt: [32 bh][64][2048] bf16 (transposed).
// Block = 4 waves; wave owns 16 q rows (q = q0 + w*16 + (lane&15)); KVBLK=128.
// S^T = mfma(K, Q): lane holds S[k = k0+nt*16+lhi*4+r][q=l16-col] -> one q per lane,
// softmax in-lane + 2 shfl. PV: O^T = mfma(V^T, P^T), P redistributed via shfl.
__global__ __launch_bounds__(256) void attn_fwd2(
    const unsigned short* __restrict__ Q, const unsigned short* __restrict__ Kp,
    const unsigned short* __restrict__ Vt, unsigned short* __restrict__ att)
{
    __shared__ __align__(16) unsigned short sK[128 * 64];   // [t][d]
    __shared__ __align__(16) unsigned short sV[64 * 128];   // [d][t]

    const int tid = threadIdx.x;
    const int lane = tid & 63;
    const int w = tid >> 6;
    const int l16 = lane & 15, lhi = lane >> 4;
    const int bh = blockIdx.x & 31;
    const int band = 31 - (blockIdx.x >> 5);   // longest bands dispatch first
    const size_t hoff = (size_t)bh * 2048 * 64;
    const unsigned short* Qh = Q + hoff;
    const unsigned short* Kh = Kp + hoff;
    const unsigned short* Vh = Vt + hoff;      // [64][2048]
    const int q0 = band * 64;
    const int qg = q0 + w * 16 + l16;          // this lane's q column

    // Q as B-operand fragments: lane l holds Q[q=l16][d = kk*32 + lhi*8 + j]
    vbf8 qf[2];
#pragma unroll
    for (int kk = 0; kk < 2; ++kk)
        qf[kk] = *(const vbf8*)&Qh[(size_t)qg * 64 + kk * 32 + lhi * 8];

    vf4 oacc[4] = {};                 // O^T[d = dt*16+lhi*4+r][q = l16]
    float m = -1e30f, lsum = 0.f;

    const int ktLast = (q0 + 63) >> 7;
    for (int kt = 0; kt <= ktLast; ++kt) {
        const int k0 = kt * 128;
        // stage K [128][64] (8 chunks/row) and Vt [64][128] (16 chunks/row), swizzled source
#pragma unroll
        for (int i = 0; i < 4; ++i) {
            int p = i * 256 + tid;
            int r = p >> 3, cb = p & 7;
            gload_lds16(Kh + (size_t)(k0 + r) * 64 + ((cb ^ (r & 7)) << 3), &sK[p << 3]);
        }
#pragma unroll
        for (int i = 0; i < 4; ++i) {
            int p = i * 256 + tid;
            int r = p >> 4, cb = p & 15;
            gload_lds16(Vh + (size_t)r * 2048 + k0 + ((cb ^ (r & 7)) << 3), &sV[p << 3]);
        }
        __syncthreads();

        // S^T: sc[nt] rows k = k0+nt*16+lhi*4+r, col q = l16
        vf4 sc[8] = {};
#pragma unroll
        for (int kk = 0; kk < 2; ++kk) {
#pragma unroll
            for (int nt = 0; nt < 8; ++nt) {
                int rr = nt * 16 + l16;
                vbf8 kf = *(const vbf8*)&sK[(rr << 6) + ((((kk << 2) + lhi) ^ (rr & 7)) << 3)];
                sc[nt] = MFMA16(kf, qf[kk], sc[nt]);
            }
        }

        // scale (+ causal mask on last tile only)
        if (kt == ktLast) {
#pragma unroll
            for (int nt = 0; nt < 8; ++nt)
#pragma unroll
                for (int r = 0; r < 4; ++r) {
                    int kg = k0 + nt * 16 + lhi * 4 + r;
                    sc[nt][r] = (kg > qg) ? -1e30f : sc[nt][r] * 0.125f;
                }
        } else {
#pragma unroll
            for (int nt = 0; nt < 8; ++nt)
#pragma unroll
                for (int r = 0; r < 4; ++r) sc[nt][r] *= 0.125f;
        }

        // online softmax: row q = qg spans lanes {l16, l16+16, l16+32, l16+48}
        float pm = -1e30f;
#pragma unroll
        for (int nt = 0; nt < 8; ++nt)
#pragma unroll
            for (int r = 0; r < 4; ++r) pm = fmaxf(pm, sc[nt][r]);
        pm = fmaxf(pm, __shfl_xor(pm, 16, 64));
        pm = fmaxf(pm, __shfl_xor(pm, 32, 64));
        float mn = fmaxf(m, pm);
        float alpha = __expf(m - mn);
        m = mn;
        float rs = 0.f;
#pragma unroll
        for (int nt = 0; nt < 8; ++nt)
#pragma unroll
            for (int r = 0; r < 4; ++r) {
                float p = __expf(sc[nt][r] - mn);
                sc[nt][r] = p;
                rs += p;
            }
        rs += __shfl_xor(rs, 16, 64);
        rs += __shfl_xor(rs, 32, 64);
        lsum = lsum * alpha + rs;
#pragma unroll
        for (int dt = 0; dt < 4; ++dt)
#pragma unroll
            for (int r = 0; r < 4; ++r) oacc[dt][r] *= alpha;

        // pack P^T to bf16 pairs: pk0/pk1[nt] cover k = k0+nt*16+lhi*4+{0,1},{2,3}
        unsigned int pk0[8], pk1[8];
#pragma unroll
        for (int nt = 0; nt < 8; ++nt) {
            pk0[nt] = (unsigned int)f2bf(sc[nt][0]) | ((unsigned int)f2bf(sc[nt][1]) << 16);
            pk1[nt] = (unsigned int)f2bf(sc[nt][2]) | ((unsigned int)f2bf(sc[nt][3]) << 16);
        }

        // PV: O^T += V^T * P^T. B-frag lane l needs P^T[k = kk*32 + lhi*8 + j][q=l16]:
        // holders share l16; nt = 2kk + (lhi>>1), holder groups hg = 2*(lhi&1), +1.
        const int srcA = l16 + ((lhi & 1) ? 32 : 0);
        const int srcB = srcA + 16;
        const bool hiSel = (lhi >> 1) != 0;
#pragma unroll
        for (int kk = 0; kk < 4; ++kk) {
            unsigned int a0e = __shfl((int)pk0[2 * kk], srcA, 64);
            unsigned int a1e = __shfl((int)pk1[2 * kk], srcA, 64);
            unsigned int b0e = __shfl((int)pk0[2 * kk], srcB, 64);
            unsigned int b1e = __shfl((int)pk1[2 * kk], srcB, 64);
            unsigned int a0o = __shfl((int)pk0[2 * kk + 1], srcA, 64);
            unsigned int a1o = __shfl((int)pk1[2 * kk + 1], srcA, 64);
            unsigned int b0o = __shfl((int)pk0[2 * kk + 1], srcB, 64);
            unsigned int b1o = __shfl((int)pk1[2 * kk + 1], srcB, 64);
            vu4 uw;
            uw.x = hiSel ? a0o : a0e;
            uw.y = hiSel ? a1o : a1e;
            uw.z = hiSel ? b0o : b0e;
            uw.w = hiSel ? b1o : b1e;
            vbf8 pf = __builtin_bit_cast(vbf8, uw);
#pragma unroll
            for (int dt = 0; dt < 4; ++dt) {
                int rr = dt * 16 + l16;
                vbf8 vfr = *(const vbf8*)&sV[(rr << 7) + ((((kk << 2) + lhi) ^ (rr & 7)) << 3)];
                oacc[dt] = MFMA16(vfr, pf, oacc[dt]);
            }
        }
        __syncthreads();
    }

    // epilogue: transpose O^T -> O via per-wave LDS strip, then coalesced bf16 store
    const float inv = 1.0f / lsum;
    unsigned short* so = &sK[w * 1024];   // 16 q x 64 d per wave
#pragma unroll
    for (int dt = 0; dt < 4; ++dt)
#pragma unroll
        for (int r = 0; r < 4; ++r)
            so[l16 * 64 + dt * 16 + lhi * 4 + r] = f2bf(oacc[dt][r] * inv);

    const int b = bh >> 4, h = bh & 15;
    const int qrow = q0 + w * 16 + (lane >> 2);
    const int c16 = (lane & 3) * 16;
    vbf8 o1 = *(const vbf8*)&so[(lane >> 2) * 64 + c16];
    vbf8 o2 = *(const vbf8*)&so[(lane >> 2) * 64 + c16 + 8];
    unsigned short* dst = att + ((size_t)(b * 2048 + qrow)) * 1024 + h * 64 + c16;
    *(vbf8*)dst = o1;
    *(vbf8*)(dst + 8) = o2;
}

// ---------------- launcher ----------------
extern "C" void kernel_launch(void* const* d_in, const int* in_sizes, int n_in,
                              void* d_out, int out_size, void* d_ws, size_t ws_size,
                              hipStream_t stream) {
    const float* x = (const float*)d_in[0];      // [2,2048,1024]
    const float* w_qkv = (const float*)d_in[1];  // [3072,1024]
    const float* w_out = (const float*)d_in[2];  // [1024,1024]
    float* out = (float*)d_out;                  // [2,2048,1024]

    char* ws = (char*)d_ws;
    unsigned short* xb   = (unsigned short*)(ws);                        // 8 MiB
    unsigned short* wqb  = (unsigned short*)(ws + (8ull << 20));         // 6 MiB
    unsigned short* wob  = (unsigned short*)(ws + (14ull << 20));        // 2 MiB
    unsigned short* Qb   = (unsigned short*)(ws + (16ull << 20));        // 8 MiB
    unsigned short* Kb   = (unsigned short*)(ws + (24ull << 20));        // 8 MiB
    unsigned short* Vb   = (unsigned short*)(ws + (32ull << 20));        // 8 MiB (transposed)
    unsigned short* attb = (unsigned short*)(ws + (40ull << 20));        // 8 MiB

    // 1) conversions
    cvt_f32_bf16<<<4096, 256, 0, stream>>>(x, xb, (2 * 2048 * 1024) / 4);
    cvt_f32_bf16<<<3072, 256, 0, stream>>>(w_qkv, wqb, (3072 * 1024) / 4);
    cvt_f32_bf16<<<1024, 256, 0, stream>>>(w_out, wob, (1024 * 1024) / 4);

    // 2) QKV projection: [4096,1024] x [3072,1024]^T -> scatter to Q/K/Vt
    gemm_bt<1><<<dim3(3072 / 128, 4096 / 128), 256, 0, stream>>>(
        xb, wqb, 4096, 3072, 1024, nullptr, Qb, Kb, Vb);

    // 3) causal attention -> attb [4096,1024] bf16
    attn_fwd2<<<32 * 32, 256, 0, stream>>>(Qb, Kb, Vb, attb);

    // 4) output projection: [4096,1024] x [1024,1024]^T -> f32 d_out
    gemm_bt<0><<<dim3(1024 / 128, 4096 / 128), 256, 0, stream>>>(
        attb, wob, 4096, 1024, 1024, out, nullptr, nullptr, nullptr);
}

// Round 3
// 124.058 us; speedup vs baseline: 1.8804x; 1.2332x over previous
//
#include <hip/hip_runtime.h>
#include <hip/hip_bf16.h>

typedef __attribute__((ext_vector_type(8))) short vbf8;   // 8 bf16 in 4 VGPRs
typedef __attribute__((ext_vector_type(4))) float vf4;    // MFMA 16x16 accumulator
typedef __attribute__((ext_vector_type(4))) unsigned int vu4;

#define MFMA16(a, b, c) __builtin_amdgcn_mfma_f32_16x16x32_bf16((a), (b), (c), 0, 0, 0)

__device__ __forceinline__ unsigned short f2bf(float f) {
    unsigned int u = __float_as_uint(f);
    u += 0x7fffu + ((u >> 16) & 1u);   // RNE
    return (unsigned short)(u >> 16);
}

// async global->LDS, 16B per lane. LDS dest must be linear (base + lane*16).
__device__ __forceinline__ void gload_lds16(const void* g, void* l) {
    __builtin_amdgcn_global_load_lds(
        (const __attribute__((address_space(1))) unsigned int*)(unsigned long long)g,
        (__attribute__((address_space(3))) unsigned int*)(unsigned long long)l,
        16, 0, 0);
}

// ---------------- fused f32 -> bf16 conversion (x, w_qkv, w_out in one launch) ----------------
__global__ __launch_bounds__(256) void cvt_all(
    const float* __restrict__ x, const float* __restrict__ wq, const float* __restrict__ wo,
    unsigned short* __restrict__ xb, unsigned short* __restrict__ wqb, unsigned short* __restrict__ wob)
{
    int i = blockIdx.x * 256 + threadIdx.x;   // float4 index, total 2097152
    const float* src;
    unsigned short* dst;
    int off;
    if (i < 1048576)      { src = x;  dst = xb;  off = i; }
    else if (i < 1835008) { src = wq; dst = wqb; off = i - 1048576; }
    else                  { src = wo; dst = wob; off = i - 1835008; }
    float4 v = ((const float4*)src)[off];
    ushort4 o;
    o.x = f2bf(v.x); o.y = f2bf(v.y); o.z = f2bf(v.z); o.w = f2bf(v.w);
    ((ushort4*)dst)[off] = o;
}

// ---------------- GEMM: C[M,N] = A[M,K] * Bt[N,K]^T, bf16 in, f32 acc ----------------
// 128x128 tile, BK=64, 4 waves (2x2 of 64x64). LDS linear, global source pre-swizzled.
// EPI=0: write f32 to Cf[M,N].  EPI=1: scatter bf16 into Q (pre-scaled by 0.125) / K [bh][t][64]
// and V TRANSPOSED [bh][64][2048].
template <int EPI>
__global__ __launch_bounds__(256) void gemm_bt(
    const unsigned short* __restrict__ A, const unsigned short* __restrict__ Bt,
    int M, int N, int K,
    float* __restrict__ Cf,
    unsigned short* __restrict__ Qo, unsigned short* __restrict__ Ko, unsigned short* __restrict__ Vo)
{
    __shared__ __align__(16) unsigned short sA[128 * 64];
    __shared__ __align__(16) unsigned short sB[128 * 64];

    const int tid = threadIdx.x;
    const int lane = tid & 63;
    const int w = tid >> 6;
    const int wr = w >> 1, wc = w & 1;
    const int l16 = lane & 15, lhi = lane >> 4;
    const int bm = blockIdx.y, bn = blockIdx.x;
    const int row0 = bm * 128, col0 = bn * 128;

    vf4 acc[4][4] = {};

    for (int k0 = 0; k0 < K; k0 += 64) {
#pragma unroll
        for (int i = 0; i < 4; ++i) {
            int p = i * 256 + tid;            // chunk id
            int r = p >> 3, cb = p & 7;
            int cs = cb ^ (r & 7);            // pre-swizzled source chunk
            gload_lds16(A + (size_t)(row0 + r) * K + k0 + (cs << 3), &sA[p << 3]);
            gload_lds16(Bt + (size_t)(col0 + r) * K + k0 + (cs << 3), &sB[p << 3]);
        }
        __syncthreads();
#pragma unroll
        for (int kk = 0; kk < 2; ++kk) {
            const int cb = kk * 4 + lhi;
            vbf8 af[4], bfr[4];
#pragma unroll
            for (int mt = 0; mt < 4; ++mt) {
                int r = wr * 64 + mt * 16 + l16;
                af[mt] = *(const vbf8*)&sA[(r << 6) + ((cb ^ (r & 7)) << 3)];
            }
#pragma unroll
            for (int nt = 0; nt < 4; ++nt) {
                int r = wc * 64 + nt * 16 + l16;
                bfr[nt] = *(const vbf8*)&sB[(r << 6) + ((cb ^ (r & 7)) << 3)];
            }
#pragma unroll
            for (int mt = 0; mt < 4; ++mt)
#pragma unroll
                for (int nt = 0; nt < 4; ++nt)
                    acc[mt][nt] = MFMA16(af[mt], bfr[nt], acc[mt][nt]);
        }
        __syncthreads();
    }

    // epilogue: C/D layout col = lane&15, row = (lane>>4)*4 + r
#pragma unroll
    for (int mt = 0; mt < 4; ++mt) {
#pragma unroll
        for (int nt = 0; nt < 4; ++nt) {
#pragma unroll
            for (int r = 0; r < 4; ++r) {
                int row = row0 + wr * 64 + mt * 16 + lhi * 4 + r;
                int col = col0 + wc * 64 + nt * 16 + l16;
                float v = acc[mt][nt][r];
                if (EPI == 0) {
                    Cf[(size_t)row * N + col] = v;
                } else {
                    // col = which*1024 + h*64 + d ; row = b*2048 + t
                    int which = col >> 10, rem = col & 1023;
                    int h = rem >> 6, d = rem & 63;
                    int b = row >> 11, t = row & 2047;
                    size_t bh = (size_t)(b * 16 + h);
                    if (which == 0)      Qo[(bh * 2048 + t) * 64 + d] = f2bf(v * 0.125f); // fused scale
                    else if (which == 1) Ko[(bh * 2048 + t) * 64 + d] = f2bf(v);
                    else                 Vo[(bh * 64 + d) * 2048 + t] = f2bf(v);  // transposed
                }
            }
        }
    }
}

// ---------------- causal flash attention, 8 waves / 128 q rows, double-buffered KV ----------------
// Q/K: [32 bh][2048][64] bf16 (Q pre-scaled by 0.125); Vt: [32 bh][64][2048] bf16.
// S^T = mfma(K, Q): lane owns one q column; softmax in-lane + 2 shfl; P redistributed by shfl;
// O^T = mfma(V^T, P^T). KV tiles of 128 double-buffered, prefetch with counted vmcnt.
__global__ __launch_bounds__(512, 4) void attn_fwd3(
    const unsigned short* __restrict__ Q, const unsigned short* __restrict__ Kp,
    const unsigned short* __restrict__ Vt, unsigned short* __restrict__ att)
{
    __shared__ __align__(16) unsigned short sK[2][128 * 64];   // [t][d]
    __shared__ __align__(16) unsigned short sV[2][64 * 128];   // [d][t]

    const int tid = threadIdx.x;
    const int lane = tid & 63;
    const int w = tid >> 6;                    // 0..7
    const int l16 = lane & 15, lhi = lane >> 4;
    const int bh = blockIdx.x & 31;
    const int band = 15 - (blockIdx.x >> 5);   // longest bands dispatch first
    const size_t hoff = (size_t)bh * 2048 * 64;
    const unsigned short* Qh = Q + hoff;
    const unsigned short* Kh = Kp + hoff;
    const unsigned short* Vh = Vt + hoff;      // [64][2048]
    const int q0 = band * 128;
    const int qg = q0 + w * 16 + l16;          // this lane's q column
    const int ktLast = band;

    // per-thread staging constants: 2 K-chunks + 2 V-chunks of 16B per tile
    const int pA = tid, pB = 512 + tid;
    const int rKA = pA >> 3, cKA = pA & 7;
    const int rKB = pB >> 3, cKB = pB & 7;
    const int rVA = pA >> 4, cVA = pA & 15;
    const int rVB = pB >> 4, cVB = pB & 15;
    const unsigned short* pKA = Kh + (size_t)rKA * 64 + ((cKA ^ (rKA & 7)) << 3);
    const unsigned short* pKB = Kh + (size_t)rKB * 64 + ((cKB ^ (rKB & 7)) << 3);
    const unsigned short* pVA = Vh + (size_t)rVA * 2048 + ((cVA ^ (rVA & 7)) << 3);
    const unsigned short* pVB = Vh + (size_t)rVB * 2048 + ((cVB ^ (rVB & 7)) << 3);
    const int dA = pA << 3, dB = pB << 3;      // lds offsets in shorts

    auto STAGE = [&](int buf, int k0) {
        gload_lds16(pKA + (size_t)k0 * 64, &sK[buf][dA]);
        gload_lds16(pKB + (size_t)k0 * 64, &sK[buf][dB]);
        gload_lds16(pVA + k0, &sV[buf][dA]);
        gload_lds16(pVB + k0, &sV[buf][dB]);
    };

    STAGE(0, 0);

    // Q as B-operand fragments: lane l holds Q[q=qg][d = kk*32 + lhi*8 + j]
    vbf8 qf[2];
#pragma unroll
    for (int kk = 0; kk < 2; ++kk)
        qf[kk] = *(const vbf8*)&Qh[(size_t)qg * 64 + kk * 32 + lhi * 8];

    vf4 oacc[4] = {};                 // O^T[d = dt*16+lhi*4+r][q = l16]
    float m = -1e30f, lsum = 0.f;

    for (int kt = 0; kt <= ktLast; ++kt) {
        const int cur = kt & 1;
        const int k0 = kt * 128;
        if (kt < ktLast) {
            STAGE(cur ^ 1, k0 + 128);
            asm volatile("s_waitcnt vmcnt(4)" ::: "memory");
        } else {
            asm volatile("s_waitcnt vmcnt(0)" ::: "memory");
        }
        __builtin_amdgcn_s_barrier();
        __builtin_amdgcn_sched_barrier(0);

        const unsigned short* sKc = &sK[cur][0];
        const unsigned short* sVc = &sV[cur][0];

        // S^T: sc[nt] rows k = k0+nt*16+lhi*4+r, col q = l16  (Q pre-scaled, no mul needed)
        vf4 sc[8] = {};
#pragma unroll
        for (int kk = 0; kk < 2; ++kk) {
#pragma unroll
            for (int nt = 0; nt < 8; ++nt) {
                int rr = nt * 16 + l16;
                vbf8 kf = *(const vbf8*)&sKc[(rr << 6) + ((((kk << 2) + lhi) ^ (rr & 7)) << 3)];
                sc[nt] = MFMA16(kf, qf[kk], sc[nt]);
            }
        }

        // causal mask on last tile only
        if (kt == ktLast) {
#pragma unroll
            for (int nt = 0; nt < 8; ++nt)
#pragma unroll
                for (int r = 0; r < 4; ++r) {
                    int kg = k0 + nt * 16 + lhi * 4 + r;
                    if (kg > qg) sc[nt][r] = -1e30f;
                }
        }

        // online softmax: row q = qg spans lanes {l16, l16+16, l16+32, l16+48}
        float pm = -1e30f;
#pragma unroll
        for (int nt = 0; nt < 8; ++nt)
#pragma unroll
            for (int r = 0; r < 4; ++r) pm = fmaxf(pm, sc[nt][r]);
        pm = fmaxf(pm, __shfl_xor(pm, 16, 64));
        pm = fmaxf(pm, __shfl_xor(pm, 32, 64));
        float mn = fmaxf(m, pm);
        float alpha = __expf(m - mn);
        m = mn;
        float rs = 0.f;
#pragma unroll
        for (int nt = 0; nt < 8; ++nt)
#pragma unroll
            for (int r = 0; r < 4; ++r) {
                float p = __expf(sc[nt][r] - mn);
                sc[nt][r] = p;
                rs += p;
            }
        rs += __shfl_xor(rs, 16, 64);
        rs += __shfl_xor(rs, 32, 64);
        lsum = lsum * alpha + rs;
#pragma unroll
        for (int dt = 0; dt < 4; ++dt)
#pragma unroll
            for (int r = 0; r < 4; ++r) oacc[dt][r] *= alpha;

        // pack P^T to bf16 pairs: pk0/pk1[nt] cover k = k0+nt*16+lhi*4+{0,1},{2,3}
        unsigned int pk0[8], pk1[8];
#pragma unroll
        for (int nt = 0; nt < 8; ++nt) {
            pk0[nt] = (unsigned int)f2bf(sc[nt][0]) | ((unsigned int)f2bf(sc[nt][1]) << 16);
            pk1[nt] = (unsigned int)f2bf(sc[nt][2]) | ((unsigned int)f2bf(sc[nt][3]) << 16);
        }

        // PV: O^T += V^T * P^T. B-frag lane l needs P^T[k = kk*32 + lhi*8 + j][q=l16]:
        const int srcA = l16 + ((lhi & 1) ? 32 : 0);
        const int srcB = srcA + 16;
        const bool hiSel = (lhi >> 1) != 0;
#pragma unroll
        for (int kk = 0; kk < 4; ++kk) {
            unsigned int a0e = __shfl((int)pk0[2 * kk], srcA, 64);
            unsigned int a1e = __shfl((int)pk1[2 * kk], srcA, 64);
            unsigned int b0e = __shfl((int)pk0[2 * kk], srcB, 64);
            unsigned int b1e = __shfl((int)pk1[2 * kk], srcB, 64);
            unsigned int a0o = __shfl((int)pk0[2 * kk + 1], srcA, 64);
            unsigned int a1o = __shfl((int)pk1[2 * kk + 1], srcA, 64);
            unsigned int b0o = __shfl((int)pk0[2 * kk + 1], srcB, 64);
            unsigned int b1o = __shfl((int)pk1[2 * kk + 1], srcB, 64);
            vu4 uw;
            uw.x = hiSel ? a0o : a0e;
            uw.y = hiSel ? a1o : a1e;
            uw.z = hiSel ? b0o : b0e;
            uw.w = hiSel ? b1o : b1e;
            vbf8 pf = __builtin_bit_cast(vbf8, uw);
#pragma unroll
            for (int dt = 0; dt < 4; ++dt) {
                int rr = dt * 16 + l16;
                vbf8 vfr = *(const vbf8*)&sVc[(rr << 7) + ((((kk << 2) + lhi) ^ (rr & 7)) << 3)];
                oacc[dt] = MFMA16(vfr, pf, oacc[dt]);
            }
        }
        __builtin_amdgcn_s_barrier();      // all waves done reading buf[cur] before next stage overwrites
        __builtin_amdgcn_sched_barrier(0);
    }

    // epilogue: transpose O^T -> O via per-wave LDS strip (XOR-swizzled), coalesced bf16 store
    const float inv = 1.0f / lsum;
    unsigned short* so = &sK[0][0] + w * 1024;   // 16 q x 64 d per wave (16 KB total)
#pragma unroll
    for (int dt = 0; dt < 4; ++dt)
#pragma unroll
        for (int r = 0; r < 4; ++r)
            so[l16 * 64 + (((dt * 2 + (lhi >> 1)) ^ (l16 & 7)) << 3) + (lhi & 1) * 4 + r] =
                f2bf(oacc[dt][r] * inv);
    __syncthreads();

    const int b = bh >> 4, h = bh & 15;
    const int qr = lane >> 2;
    const int cj = lane & 3;
    vbf8 o1 = *(const vbf8*)&so[qr * 64 + (((cj * 2 + 0) ^ (qr & 7)) << 3)];
    vbf8 o2 = *(const vbf8*)&so[qr * 64 + (((cj * 2 + 1) ^ (qr & 7)) << 3)];
    const int qrow = q0 + w * 16 + qr;
    unsigned short* dst = att + ((size_t)(b * 2048 + qrow)) * 1024 + h * 64 + cj * 16;
    *(vbf8*)dst = o1;
    *(vbf8*)(dst + 8) = o2;
}

// ---------------- launcher ----------------
extern "C" void kernel_launch(void* const* d_in, const int* in_sizes, int n_in,
                              void* d_out, int out_size, void* d_ws, size_t ws_size,
                              hipStream_t stream) {
    const float* x = (const float*)d_in[0];      // [2,2048,1024]
    const float* w_qkv = (const float*)d_in[1];  // [3072,1024]
    const float* w_out = (const float*)d_in[2];  // [1024,1024]
    float* out = (float*)d_out;                  // [2,2048,1024]

    char* ws = (char*)d_ws;
    unsigned short* xb   = (unsigned short*)(ws);                        // 8 MiB
    unsigned short* wqb  = (unsigned short*)(ws + (8ull << 20));         // 6 MiB
    unsigned short* wob  = (unsigned short*)(ws + (14ull << 20));        // 2 MiB
    unsigned short* Qb   = (unsigned short*)(ws + (16ull << 20));        // 8 MiB (pre-scaled)
    unsigned short* Kb   = (unsigned short*)(ws + (24ull << 20));        // 8 MiB
    unsigned short* Vb   = (unsigned short*)(ws + (32ull << 20));        // 8 MiB (transposed)
    unsigned short* attb = (unsigned short*)(ws + (40ull << 20));        // 8 MiB

    // 1) fused conversions
    cvt_all<<<8192, 256, 0, stream>>>(x, w_qkv, w_out, xb, wqb, wob);

    // 2) QKV projection: [4096,1024] x [3072,1024]^T -> scatter to Q/K/Vt
    gemm_bt<1><<<dim3(3072 / 128, 4096 / 128), 256, 0, stream>>>(
        xb, wqb, 4096, 3072, 1024, nullptr, Qb, Kb, Vb);

    // 3) causal attention -> attb [4096,1024] bf16
    attn_fwd3<<<16 * 32, 512, 0, stream>>>(Qb, Kb, Vb, attb);

    // 4) output projection: [4096,1024] x [1024,1024]^T -> f32 d_out
    gemm_bt<0><<<dim3(1024 / 128, 4096 / 128), 256, 0, stream>>>(
        attb, wob, 4096, 1024, 1024, out, nullptr, nullptr, nullptr);
}

// Round 4
// 118.390 us; speedup vs baseline: 1.9704x; 1.0479x over previous
//
#include <hip/hip_runtime.h>
#include <hip/hip_bf16.h>

typedef __attribute__((ext_vector_type(8))) short vbf8;   // 8 bf16 in 4 VGPRs
typedef __attribute__((ext_vector_type(4))) float vf4;    // MFMA 16x16 accumulator
typedef __attribute__((ext_vector_type(4))) unsigned int vu4;

#define MFMA16(a, b, c) __builtin_amdgcn_mfma_f32_16x16x32_bf16((a), (b), (c), 0, 0, 0)

__device__ __forceinline__ unsigned short f2bf(float f) {
    unsigned int u = __float_as_uint(f);
    u += 0x7fffu + ((u >> 16) & 1u);   // RNE
    return (unsigned short)(u >> 16);
}

// packed f32x2 -> bf16x2 (RNE), non-volatile so the scheduler can reorder
__device__ __forceinline__ unsigned int cvtpk(float a, float b) {
    unsigned int r;
    asm("v_cvt_pk_bf16_f32 %0, %1, %2" : "=v"(r) : "v"(a), "v"(b));
    return r;
}

// async global->LDS, 16B per lane. LDS dest must be linear (base + lane*16).
__device__ __forceinline__ void gload_lds16(const void* g, void* l) {
    __builtin_amdgcn_global_load_lds(
        (const __attribute__((address_space(1))) unsigned int*)(unsigned long long)g,
        (__attribute__((address_space(3))) unsigned int*)(unsigned long long)l,
        16, 0, 0);
}

// ---------------- fused f32 -> bf16 conversion (x, w_qkv, w_out in one launch) ----------------
__global__ __launch_bounds__(256) void cvt_all(
    const float* __restrict__ x, const float* __restrict__ wq, const float* __restrict__ wo,
    unsigned short* __restrict__ xb, unsigned short* __restrict__ wqb, unsigned short* __restrict__ wob)
{
    int i = blockIdx.x * 256 + threadIdx.x;   // float4 index, total 2097152
    const float* src;
    unsigned short* dst;
    int off;
    if (i < 1048576)      { src = x;  dst = xb;  off = i; }
    else if (i < 1835008) { src = wq; dst = wqb; off = i - 1048576; }
    else                  { src = wo; dst = wob; off = i - 1835008; }
    float4 v = ((const float4*)src)[off];
    ushort4 o;
    o.x = f2bf(v.x); o.y = f2bf(v.y); o.z = f2bf(v.z); o.w = f2bf(v.w);
    ((ushort4*)dst)[off] = o;
}

// ---------------- GEMM: C[M,N] = A[M,K] * Bt[N,K]^T, bf16 in, f32 acc ----------------
// 128x128 tile, BK=64, 4 waves (2x2 of 64x64). LDS linear, global source pre-swizzled.
// EPI=0: write f32 to Cf[M,N].  EPI=1: scatter bf16 into Q (pre-scaled by 0.125*log2e) /
// K [bh][t][64] and V TRANSPOSED [bh][64][2048].
template <int EPI>
__global__ __launch_bounds__(256) void gemm_bt(
    const unsigned short* __restrict__ A, const unsigned short* __restrict__ Bt,
    int M, int N, int K,
    float* __restrict__ Cf,
    unsigned short* __restrict__ Qo, unsigned short* __restrict__ Ko, unsigned short* __restrict__ Vo)
{
    __shared__ __align__(16) unsigned short sA[128 * 64];
    __shared__ __align__(16) unsigned short sB[128 * 64];

    const int tid = threadIdx.x;
    const int lane = tid & 63;
    const int w = tid >> 6;
    const int wr = w >> 1, wc = w & 1;
    const int l16 = lane & 15, lhi = lane >> 4;
    const int bm = blockIdx.y, bn = blockIdx.x;
    const int row0 = bm * 128, col0 = bn * 128;

    vf4 acc[4][4] = {};

    for (int k0 = 0; k0 < K; k0 += 64) {
#pragma unroll
        for (int i = 0; i < 4; ++i) {
            int p = i * 256 + tid;            // chunk id
            int r = p >> 3, cb = p & 7;
            int cs = cb ^ (r & 7);            // pre-swizzled source chunk
            gload_lds16(A + (size_t)(row0 + r) * K + k0 + (cs << 3), &sA[p << 3]);
            gload_lds16(Bt + (size_t)(col0 + r) * K + k0 + (cs << 3), &sB[p << 3]);
        }
        __syncthreads();
#pragma unroll
        for (int kk = 0; kk < 2; ++kk) {
            const int cb = kk * 4 + lhi;
            vbf8 af[4], bfr[4];
#pragma unroll
            for (int mt = 0; mt < 4; ++mt) {
                int r = wr * 64 + mt * 16 + l16;
                af[mt] = *(const vbf8*)&sA[(r << 6) + ((cb ^ (r & 7)) << 3)];
            }
#pragma unroll
            for (int nt = 0; nt < 4; ++nt) {
                int r = wc * 64 + nt * 16 + l16;
                bfr[nt] = *(const vbf8*)&sB[(r << 6) + ((cb ^ (r & 7)) << 3)];
            }
#pragma unroll
            for (int mt = 0; mt < 4; ++mt)
#pragma unroll
                for (int nt = 0; nt < 4; ++nt)
                    acc[mt][nt] = MFMA16(af[mt], bfr[nt], acc[mt][nt]);
        }
        __syncthreads();
    }

    // epilogue: C/D layout col = lane&15, row = (lane>>4)*4 + r
#pragma unroll
    for (int mt = 0; mt < 4; ++mt) {
#pragma unroll
        for (int nt = 0; nt < 4; ++nt) {
#pragma unroll
            for (int r = 0; r < 4; ++r) {
                int row = row0 + wr * 64 + mt * 16 + lhi * 4 + r;
                int col = col0 + wc * 64 + nt * 16 + l16;
                float v = acc[mt][nt][r];
                if (EPI == 0) {
                    Cf[(size_t)row * N + col] = v;
                } else {
                    // col = which*1024 + h*64 + d ; row = b*2048 + t
                    int which = col >> 10, rem = col & 1023;
                    int h = rem >> 6, d = rem & 63;
                    int b = row >> 11, t = row & 2047;
                    size_t bh = (size_t)(b * 16 + h);
                    // Q pre-scaled by 0.125 * log2(e) so attention can use exp2 directly
                    if (which == 0)      Qo[(bh * 2048 + t) * 64 + d] = f2bf(v * 0.18033688011112042f);
                    else if (which == 1) Ko[(bh * 2048 + t) * 64 + d] = f2bf(v);
                    else                 Vo[(bh * 64 + d) * 2048 + t] = f2bf(v);  // transposed
                }
            }
        }
    }
}

// ---------------- causal flash attention, 8 waves / 128 q rows, double-buffered KV ----------------
// Q/K: [32 bh][2048][64] bf16 (Q pre-scaled by 0.125*log2e); Vt: [32 bh][64][2048] bf16.
// S^T = mfma(K, Q): lane owns one q column; softmax in-lane (exp2, defer-max) + 2 shfl;
// P packed via v_cvt_pk_bf16_f32, redistributed by shfl; O^T = mfma(V^T, P^T).
__global__ __launch_bounds__(512, 4) void attn_fwd4(
    const unsigned short* __restrict__ Q, const unsigned short* __restrict__ Kp,
    const unsigned short* __restrict__ Vt, unsigned short* __restrict__ att)
{
    __shared__ __align__(16) unsigned short sK[2][128 * 64];   // [t][d]
    __shared__ __align__(16) unsigned short sV[2][64 * 128];   // [d][t]

    const int tid = threadIdx.x;
    const int lane = tid & 63;
    const int w = tid >> 6;                    // 0..7
    const int l16 = lane & 15, lhi = lane >> 4;
    const int bh = blockIdx.x & 31;
    // band pairing for load balance: order 15..8 then 0..7 so the two co-resident
    // blocks per CU sum to ~15-16 tile-iterations instead of 10..24.
    const int j = blockIdx.x >> 5;
    const int band = (j < 8) ? (15 - j) : (j - 8);
    const size_t hoff = (size_t)bh * 2048 * 64;
    const unsigned short* Qh = Q + hoff;
    const unsigned short* Kh = Kp + hoff;
    const unsigned short* Vh = Vt + hoff;      // [64][2048]
    const int q0 = band * 128;
    const int qg = q0 + w * 16 + l16;          // this lane's q column
    const int ktLast = band;

    // per-thread staging constants: 2 K-chunks + 2 V-chunks of 16B per tile
    const int pA = tid, pB = 512 + tid;
    const int rKA = pA >> 3, cKA = pA & 7;
    const int rKB = pB >> 3, cKB = pB & 7;
    const int rVA = pA >> 4, cVA = pA & 15;
    const int rVB = pB >> 4, cVB = pB & 15;
    const unsigned short* pKA = Kh + (size_t)rKA * 64 + ((cKA ^ (rKA & 7)) << 3);
    const unsigned short* pKB = Kh + (size_t)rKB * 64 + ((cKB ^ (rKB & 7)) << 3);
    const unsigned short* pVA = Vh + (size_t)rVA * 2048 + ((cVA ^ (rVA & 7)) << 3);
    const unsigned short* pVB = Vh + (size_t)rVB * 2048 + ((cVB ^ (rVB & 7)) << 3);
    const int dA = pA << 3, dB = pB << 3;      // lds offsets in shorts

    auto STAGE = [&](int buf, int k0) {
        gload_lds16(pKA + (size_t)k0 * 64, &sK[buf][dA]);
        gload_lds16(pKB + (size_t)k0 * 64, &sK[buf][dB]);
        gload_lds16(pVA + k0, &sV[buf][dA]);
        gload_lds16(pVB + k0, &sV[buf][dB]);
    };

    STAGE(0, 0);

    // Q as B-operand fragments: lane l holds Q[q=qg][d = kk*32 + lhi*8 + j]
    vbf8 qf[2];
#pragma unroll
    for (int kk = 0; kk < 2; ++kk)
        qf[kk] = *(const vbf8*)&Qh[(size_t)qg * 64 + kk * 32 + lhi * 8];

    vf4 oacc[4] = {};                 // O^T[d = dt*16+lhi*4+r][q = l16]
    float m = -1e30f, lsum = 0.f;

    for (int kt = 0; kt <= ktLast; ++kt) {
        const int cur = kt & 1;
        const int k0 = kt * 128;
        if (kt < ktLast) {
            STAGE(cur ^ 1, k0 + 128);
            asm volatile("s_waitcnt vmcnt(4)" ::: "memory");
        } else {
            asm volatile("s_waitcnt vmcnt(0)" ::: "memory");
        }
        __builtin_amdgcn_s_barrier();
        __builtin_amdgcn_sched_barrier(0);

        const unsigned short* sKc = &sK[cur][0];
        const unsigned short* sVc = &sV[cur][0];

        // S^T (log2-scaled): sc[nt] rows k = k0+nt*16+lhi*4+r, col q = l16
        vf4 sc[8] = {};
#pragma unroll
        for (int kk = 0; kk < 2; ++kk) {
#pragma unroll
            for (int nt = 0; nt < 8; ++nt) {
                int rr = nt * 16 + l16;
                vbf8 kf = *(const vbf8*)&sKc[(rr << 6) + ((((kk << 2) + lhi) ^ (rr & 7)) << 3)];
                sc[nt] = MFMA16(kf, qf[kk], sc[nt]);
            }
        }

        // causal mask on last tile only
        if (kt == ktLast) {
#pragma unroll
            for (int nt = 0; nt < 8; ++nt)
#pragma unroll
                for (int r = 0; r < 4; ++r) {
                    int kg = k0 + nt * 16 + lhi * 4 + r;
                    if (kg > qg) sc[nt][r] = -1e30f;
                }
        }

        // row max, tree-shaped; row q = qg spans lanes {l16, l16+16, l16+32, l16+48}
        float m4[8];
#pragma unroll
        for (int nt = 0; nt < 8; ++nt)
            m4[nt] = fmaxf(fmaxf(sc[nt][0], sc[nt][1]), fmaxf(sc[nt][2], sc[nt][3]));
        float pm = fmaxf(fmaxf(fmaxf(m4[0], m4[1]), fmaxf(m4[2], m4[3])),
                         fmaxf(fmaxf(m4[4], m4[5]), fmaxf(m4[6], m4[7])));
        pm = fmaxf(pm, __shfl_xor(pm, 16, 64));
        pm = fmaxf(pm, __shfl_xor(pm, 32, 64));

        // defer-max (T13): only rescale when the running max grew by > 8 (log2 units)
        if (!__all(pm - m <= 8.0f)) {
            float mn = fmaxf(m, pm);
            float alpha = exp2f(m - mn);
            lsum *= alpha;
#pragma unroll
            for (int dt = 0; dt < 4; ++dt)
#pragma unroll
                for (int r = 0; r < 4; ++r) oacc[dt][r] *= alpha;
            m = mn;
        }

        // P = exp2(S - m), tree-summed
        float rs4[8];
#pragma unroll
        for (int nt = 0; nt < 8; ++nt) {
#pragma unroll
            for (int r = 0; r < 4; ++r) sc[nt][r] = exp2f(sc[nt][r] - m);
            rs4[nt] = (sc[nt][0] + sc[nt][1]) + (sc[nt][2] + sc[nt][3]);
        }
        float rs = ((rs4[0] + rs4[1]) + (rs4[2] + rs4[3])) +
                   ((rs4[4] + rs4[5]) + (rs4[6] + rs4[7]));
        rs += __shfl_xor(rs, 16, 64);
        rs += __shfl_xor(rs, 32, 64);
        lsum += rs;

        // pack P^T to bf16 pairs with v_cvt_pk_bf16_f32
        unsigned int pk0[8], pk1[8];
#pragma unroll
        for (int nt = 0; nt < 8; ++nt) {
            pk0[nt] = cvtpk(sc[nt][0], sc[nt][1]);
            pk1[nt] = cvtpk(sc[nt][2], sc[nt][3]);
        }

        // PV: O^T += V^T * P^T. B-frag lane l needs P^T[k = kk*32 + lhi*8 + j][q=l16]:
        const int srcA = l16 + ((lhi & 1) ? 32 : 0);
        const int srcB = srcA + 16;
        const bool hiSel = (lhi >> 1) != 0;
#pragma unroll
        for (int kk = 0; kk < 4; ++kk) {
            unsigned int a0e = __shfl((int)pk0[2 * kk], srcA, 64);
            unsigned int a1e = __shfl((int)pk1[2 * kk], srcA, 64);
            unsigned int b0e = __shfl((int)pk0[2 * kk], srcB, 64);
            unsigned int b1e = __shfl((int)pk1[2 * kk], srcB, 64);
            unsigned int a0o = __shfl((int)pk0[2 * kk + 1], srcA, 64);
            unsigned int a1o = __shfl((int)pk1[2 * kk + 1], srcA, 64);
            unsigned int b0o = __shfl((int)pk0[2 * kk + 1], srcB, 64);
            unsigned int b1o = __shfl((int)pk1[2 * kk + 1], srcB, 64);
            vu4 uw;
            uw.x = hiSel ? a0o : a0e;
            uw.y = hiSel ? a1o : a1e;
            uw.z = hiSel ? b0o : b0e;
            uw.w = hiSel ? b1o : b1e;
            vbf8 pf = __builtin_bit_cast(vbf8, uw);
#pragma unroll
            for (int dt = 0; dt < 4; ++dt) {
                int rr = dt * 16 + l16;
                vbf8 vfr = *(const vbf8*)&sVc[(rr << 7) + ((((kk << 2) + lhi) ^ (rr & 7)) << 3)];
                oacc[dt] = MFMA16(vfr, pf, oacc[dt]);
            }
        }
        __builtin_amdgcn_s_barrier();      // all waves done reading buf[cur] before next stage overwrites
        __builtin_amdgcn_sched_barrier(0);
    }

    // epilogue: transpose O^T -> O via per-wave LDS strip (XOR-swizzled), coalesced bf16 store
    const float inv = 1.0f / lsum;
    unsigned short* so = &sK[0][0] + w * 1024;   // 16 q x 64 d per wave (16 KB total)
#pragma unroll
    for (int dt = 0; dt < 4; ++dt)
#pragma unroll
        for (int r = 0; r < 4; ++r)
            so[l16 * 64 + (((dt * 2 + (lhi >> 1)) ^ (l16 & 7)) << 3) + (lhi & 1) * 4 + r] =
                f2bf(oacc[dt][r] * inv);
    __syncthreads();

    const int b = bh >> 4, h = bh & 15;
    const int qr = lane >> 2;
    const int cj = lane & 3;
    vbf8 o1 = *(const vbf8*)&so[qr * 64 + (((cj * 2 + 0) ^ (qr & 7)) << 3)];
    vbf8 o2 = *(const vbf8*)&so[qr * 64 + (((cj * 2 + 1) ^ (qr & 7)) << 3)];
    const int qrow = q0 + w * 16 + qr;
    unsigned short* dst = att + ((size_t)(b * 2048 + qrow)) * 1024 + h * 64 + cj * 16;
    *(vbf8*)dst = o1;
    *(vbf8*)(dst + 8) = o2;
}

// ---------------- launcher ----------------
extern "C" void kernel_launch(void* const* d_in, const int* in_sizes, int n_in,
                              void* d_out, int out_size, void* d_ws, size_t ws_size,
                              hipStream_t stream) {
    const float* x = (const float*)d_in[0];      // [2,2048,1024]
    const float* w_qkv = (const float*)d_in[1];  // [3072,1024]
    const float* w_out = (const float*)d_in[2];  // [1024,1024]
    float* out = (float*)d_out;                  // [2,2048,1024]

    char* ws = (char*)d_ws;
    unsigned short* xb   = (unsigned short*)(ws);                        // 8 MiB
    unsigned short* wqb  = (unsigned short*)(ws + (8ull << 20));         // 6 MiB
    unsigned short* wob  = (unsigned short*)(ws + (14ull << 20));        // 2 MiB
    unsigned short* Qb   = (unsigned short*)(ws + (16ull << 20));        // 8 MiB (pre-scaled)
    unsigned short* Kb   = (unsigned short*)(ws + (24ull << 20));        // 8 MiB
    unsigned short* Vb   = (unsigned short*)(ws + (32ull << 20));        // 8 MiB (transposed)
    unsigned short* attb = (unsigned short*)(ws + (40ull << 20));        // 8 MiB

    // 1) fused conversions
    cvt_all<<<8192, 256, 0, stream>>>(x, w_qkv, w_out, xb, wqb, wob);

    // 2) QKV projection: [4096,1024] x [3072,1024]^T -> scatter to Q/K/Vt
    gemm_bt<1><<<dim3(3072 / 128, 4096 / 128), 256, 0, stream>>>(
        xb, wqb, 4096, 3072, 1024, nullptr, Qb, Kb, Vb);

    // 3) causal attention -> attb [4096,1024] bf16
    attn_fwd4<<<16 * 32, 512, 0, stream>>>(Qb, Kb, Vb, attb);

    // 4) output projection: [4096,1024] x [1024,1024]^T -> f32 d_out
    gemm_bt<0><<<dim3(1024 / 128, 4096 / 128), 256, 0, stream>>>(
        attb, wob, 4096, 1024, 1024, out, nullptr, nullptr, nullptr);
}